// Round 10
// baseline (470.093 us; speedup 1.0000x reference)
//
#include <hip/hip_runtime.h>
#include <hip/hip_bf16.h>

#define NN 40000
#define NE 640000
#define NG 2048
#define DD 128
#define NT 10
#define NL 5
#define NB 80  // dst buckets of 512 nodes

typedef __attribute__((ext_vector_type(8))) short short8;
typedef __attribute__((ext_vector_type(4))) float f32x4;
typedef unsigned short ushort_t;

static __device__ __forceinline__ ushort_t f2b(float f) {
    return __bfloat16_as_ushort(__float2bfloat16(f));
}
static __device__ __forceinline__ float b2f(ushort_t u) {
    return __bfloat162float(__ushort_as_bfloat16(u));
}

// ---------------- fused setup: tables + atom-encode + degree histogram -----
// blocks [0,1280): W1P/W2P/ebsum16 tables; [1280,21280): atom (2 nodes/blk);
// [21280,23780): deg histogram (256 edges/blk).
__global__ void __launch_bounds__(256)
k_setup(const float* __restrict__ W1, const float* __restrict__ W2,
        const float* __restrict__ bemb, const int* __restrict__ xa,
        const float* __restrict__ aemb, const int* __restrict__ ei,
        ushort_t* __restrict__ W1P, ushort_t* __restrict__ W2P,
        ushort_t* __restrict__ ebsum16, ushort_t* __restrict__ x16,
        int* __restrict__ deg) {
    int b = blockIdx.x, t = threadIdx.x;
    if (b < 1280) {
        int tid = b * 256 + t;  // < NL*65536
        int layer = tid >> 16;
        int r = tid & 65535;
        int half = r >> 15;
        int q = r & 32767;
        int j = q & 7;
        int lane = (q >> 3) & 63;
        if (half == 0) {
            int kk = (q >> 9) & 3;
            int nt = q >> 11;
            int n = nt * 16 + (lane & 15);
            int k = kk * 32 + (lane >> 4) * 8 + j;
            W1P[layer * 32768 + q] = f2b(W1[(layer * DD + k) * 256 + n]);
        } else {
            int kk = (q >> 9) & 7;
            int nt = q >> 12;
            int n = nt * 16 + (lane & 15);
            int k = kk * 32 + (lane >> 4) * 8 + j;
            W2P[layer * 32768 + q] = f2b(W2[(layer * 256 + k) * DD + n]);
        }
        int d = tid & 127;
        int c = (tid >> 7) & 511;
        const float* bl = bemb + (size_t)layer * 3 * 8 * DD;
        ebsum16[tid] = f2b(bl[(c & 7) * DD + d] + bl[(8 + ((c >> 3) & 7)) * DD + d] +
                           bl[(16 + (c >> 6)) * DD + d]);
    } else if (b < 21280) {
        int half = t >> 7, d = t & 127;
        int n = (b - 1280) * 2 + half;
        __shared__ int idx[2][9];
        if (d < 9) idx[half][d] = xa[n * 9 + d];
        __syncthreads();
        float s = 0.f;
#pragma unroll
        for (int f = 0; f < 9; ++f) s += aemb[(f * 64 + idx[half][f]) * DD + d];
        x16[n * DD + d] = f2b(s);
    } else {
        int e = (b - 21280) * 256 + t;
        atomicAdd(&deg[ei[NE + e]], 1);
    }
}

// ---------------- CSR build -----------------------------------------------

__global__ void k_scan1(const int* __restrict__ deg, int* __restrict__ off,
                        int* __restrict__ blksum) {
    int b = blockIdx.x, t = threadIdx.x;
    int i = b * 256 + t;
    __shared__ int s[256];
    int v = (i < NN) ? deg[i] : 0;
    s[t] = v;
    __syncthreads();
    for (int d = 1; d < 256; d <<= 1) {
        int add = (t >= d) ? s[t - d] : 0;
        __syncthreads();
        s[t] += add;
        __syncthreads();
    }
    if (i <= NN) off[i] = s[t] - v;
    if (t == 255) blksum[b] = s[255];
}

__global__ void k_scan2(int* __restrict__ blk) {
    int t = threadIdx.x;
    __shared__ int s[256];
    int v = blk[t];
    s[t] = v;
    __syncthreads();
    for (int d = 1; d < 256; d <<= 1) {
        int add = (t >= d) ? s[t - d] : 0;
        __syncthreads();
        s[t] += add;
        __syncthreads();
    }
    blk[256 + t] = s[t] - v;  // exclusive
}

__global__ void k_scan3(int* __restrict__ off, const int* __restrict__ blk) {
    int b = blockIdx.x, t = threadIdx.x;
    int i = b * 256 + t;
    if (i <= NN) off[i] += blk[256 + b];
}

// Phase A: bin edges by dst bucket into dense runs of ebuf.
__global__ void __launch_bounds__(256)
k_bucket(const int* __restrict__ ei, const int* __restrict__ ea,
         const int* __restrict__ off, int* __restrict__ gbk,
         int2* __restrict__ ebuf) {
    __shared__ int hist[NB];
    __shared__ int sbase[NB];
    int t = threadIdx.x;
    int e0 = blockIdx.x * 1024;
    if (t < NB) hist[t] = 0;
    __syncthreads();
    int rank[4], buck[4], rec[4], dstv[4];
#pragma unroll
    for (int k = 0; k < 4; ++k) {
        int e = e0 + k * 256 + t;
        int src = ei[e];
        int dst = ei[NE + e];
        int a0 = ea[e * 3 + 0], a1 = ea[e * 3 + 1], a2 = ea[e * 3 + 2];
        rec[k] = src | ((a0 | (a1 << 3) | (a2 << 6)) << 16);
        dstv[k] = dst;
        int b = dst >> 9;
        buck[k] = b;
        rank[k] = atomicAdd(&hist[b], 1);
    }
    __syncthreads();
    if (t < NB) sbase[t] = atomicAdd(&gbk[t], hist[t]);
    __syncthreads();
#pragma unroll
    for (int k = 0; k < 4; ++k) {
        int b = buck[k];
        int slot = off[b << 9] + sbase[b] + rank[k];
        ebuf[slot] = make_int2(rec[k], dstv[k]);
    }
}

// Phase B: scatter within L2-resident bucket windows.
__global__ void k_scatter2(const int2* __restrict__ ebuf, const int* __restrict__ off,
                           int* __restrict__ cursor, int2* __restrict__ epack) {
    int i = blockIdx.x * 256 + threadIdx.x;
    int2 s = ebuf[i];
    int dst = s.y;
    int p = off[dst] + atomicAdd(&cursor[dst], 1);
    epack[p] = make_int2(s.x & 0xFFFF, s.x >> 16);
}

// Gather: wave per node, lane handles 2 dims (ushort2). 4 nodes/block.
// 8-wide masked pipeline: 8 epack prefetch + 16 row loads in flight.
__global__ void __launch_bounds__(256)
k_gather(const ushort_t* __restrict__ xin, const int* __restrict__ off,
         const int2* __restrict__ epack, const ushort_t* __restrict__ ebsum16,
         const float* __restrict__ eps, int layer, ushort_t* __restrict__ h16) {
    int t = threadIdx.x;
    int lane = t & 63;
    int n = blockIdx.x * 4 + (t >> 6);
    const ushort2* x2 = (const ushort2*)xin;
    const ushort2* eb2 = (const ushort2*)ebsum16;
    ushort2 xv = x2[n * 64 + lane];
    float es = 1.f + eps[layer];
    float ax = es * b2f(xv.x), ay = es * b2f(xv.y);
    int p = off[n], p1 = off[n + 1];

    if (p < p1) {
        int2 e[8];
#pragma unroll
        for (int j = 0; j < 8; ++j) e[j] = epack[(p + j < p1) ? p + j : p1 - 1];
        while (p < p1) {
            int np = p + 8;
            int2 f[8];
            bool nh = np < p1;
            if (nh) {
#pragma unroll
                for (int j = 0; j < 8; ++j) f[j] = epack[(np + j < p1) ? np + j : p1 - 1];
            }
            ushort2 v[8], s[8];
#pragma unroll
            for (int j = 0; j < 8; ++j) {
                v[j] = eb2[e[j].y * 64 + lane];
                s[j] = x2[e[j].x * 64 + lane];
            }
#pragma unroll
            for (int j = 0; j < 8; ++j) {
                if (p + j < p1) {
                    ax += fmaxf(b2f(v[j].x) + b2f(s[j].x), 0.f);
                    ay += fmaxf(b2f(v[j].y) + b2f(s[j].y), 0.f);
                }
            }
#pragma unroll
            for (int j = 0; j < 8; ++j) e[j] = f[j];
            p = np;
        }
    }
    ushort2 o;
    o.x = f2b(ax);
    o.y = f2b(ay);
    ((ushort2*)h16)[n * 64 + lane] = o;
}

// Fused MLP on MFMA: 32 nodes per block, 256 threads (4 waves). Each B-frag
// load feeds 2 MFMAs (two A row-tiles).
__global__ void __launch_bounds__(256)
k_mlp_mfma(const ushort_t* __restrict__ h16, const ushort_t* __restrict__ W1P,
           const ushort_t* __restrict__ W2P, const float* __restrict__ b1,
           const float* __restrict__ g1, const float* __restrict__ bt1,
           const float* __restrict__ m1, const float* __restrict__ v1,
           const float* __restrict__ b2_, const float* __restrict__ gO,
           const float* __restrict__ btO, const float* __restrict__ mO,
           const float* __restrict__ vO, int relu, ushort_t* __restrict__ xout) {
    __shared__ ushort_t aS[32 * 136];   // 32 rows x 128 (pad +8)
    __shared__ ushort_t mid[32 * 264];  // 32 rows x 256 (pad +8)
    int t = threadIdx.x;
    int wave = t >> 6, lane = t & 63;
    int row0 = blockIdx.x * 32;
    int lrow = lane & 15, quad = lane >> 4;

#pragma unroll
    for (int ps = 0; ps < 2; ++ps) {
        int idx = ps * 256 + t;
        int r = idx >> 4, c = (idx & 15) * 8;
        *(short8*)&aS[r * 136 + c] = *(const short8*)&h16[(row0 + r) * DD + c];
    }
    __syncthreads();

    f32x4 acc1[2][4];
#pragma unroll
    for (int rt = 0; rt < 2; ++rt)
#pragma unroll
        for (int i = 0; i < 4; ++i) acc1[rt][i] = (f32x4){0.f, 0.f, 0.f, 0.f};
#pragma unroll
    for (int kk = 0; kk < 4; ++kk) {
        short8 af0 = *(const short8*)&aS[lrow * 136 + kk * 32 + quad * 8];
        short8 af1 = *(const short8*)&aS[(16 + lrow) * 136 + kk * 32 + quad * 8];
#pragma unroll
        for (int i = 0; i < 4; ++i) {
            int nt = wave * 4 + i;
            short8 bf = *(const short8*)&W1P[((nt * 4 + kk) * 64 + lane) * 8];
            acc1[0][i] = __builtin_amdgcn_mfma_f32_16x16x32_bf16(af0, bf, acc1[0][i], 0, 0, 0);
            acc1[1][i] = __builtin_amdgcn_mfma_f32_16x16x32_bf16(af1, bf, acc1[1][i], 0, 0, 0);
        }
    }
#pragma unroll
    for (int i = 0; i < 4; ++i) {
        int col = (wave * 4 + i) * 16 + lrow;
        float s1 = g1[col] * rsqrtf(v1[col] + 1e-5f);
        float sh = bt1[col] - (m1[col] - b1[col]) * s1;
#pragma unroll
        for (int rt = 0; rt < 2; ++rt)
#pragma unroll
            for (int r = 0; r < 4; ++r) {
                int row = rt * 16 + quad * 4 + r;
                float o = acc1[rt][i][r] * s1 + sh;
                mid[row * 264 + col] = f2b(fmaxf(o, 0.f));
            }
    }
    __syncthreads();

    f32x4 acc2[2][2];
#pragma unroll
    for (int rt = 0; rt < 2; ++rt)
#pragma unroll
        for (int i = 0; i < 2; ++i) acc2[rt][i] = (f32x4){0.f, 0.f, 0.f, 0.f};
#pragma unroll
    for (int kk = 0; kk < 8; ++kk) {
        short8 af0 = *(const short8*)&mid[lrow * 264 + kk * 32 + quad * 8];
        short8 af1 = *(const short8*)&mid[(16 + lrow) * 264 + kk * 32 + quad * 8];
#pragma unroll
        for (int i = 0; i < 2; ++i) {
            int nt = wave * 2 + i;
            short8 bf = *(const short8*)&W2P[((nt * 8 + kk) * 64 + lane) * 8];
            acc2[0][i] = __builtin_amdgcn_mfma_f32_16x16x32_bf16(af0, bf, acc2[0][i], 0, 0, 0);
            acc2[1][i] = __builtin_amdgcn_mfma_f32_16x16x32_bf16(af1, bf, acc2[1][i], 0, 0, 0);
        }
    }
#pragma unroll
    for (int i = 0; i < 2; ++i) {
        int col = (wave * 2 + i) * 16 + lrow;
        float s = gO[col] * rsqrtf(vO[col] + 1e-5f);
        float sh = btO[col] - (mO[col] - b2_[col]) * s;
#pragma unroll
        for (int rt = 0; rt < 2; ++rt)
#pragma unroll
            for (int r = 0; r < 4; ++r) {
                int row = rt * 16 + quad * 4 + r;
                float o = acc2[rt][i][r] * s + sh;
                if (relu) o = fmaxf(o, 0.f);
                xout[(row0 + row) * DD + col] = f2b(o);
            }
    }
}

// Fused pool+head: block g reduces its node range, then computes out[g].
__global__ void k_poolhead(const ushort_t* __restrict__ x16,
                           const int* __restrict__ batch,
                           const float* __restrict__ Wp, const float* __restrict__ bp,
                           float* __restrict__ out) {
    int g = blockIdx.x, d = threadIdx.x;  // 128 threads
    int lo = 0, hi = NN;
    while (lo < hi) { int m = (lo + hi) >> 1; if (batch[m] < g) lo = m + 1; else hi = m; }
    int start = lo;
    hi = NN;
    while (lo < hi) { int m = (lo + hi) >> 1; if (batch[m] < g + 1) lo = m + 1; else hi = m; }
    int end = lo;
    float s = 0.f;
    for (int n = start; n < end; ++n) s += b2f(x16[n * DD + d]);
    float c = fmaxf((float)(end - start), 1.f);
    __shared__ float p[DD];
    p[d] = s / c;
    __syncthreads();
    if (d < NT) {
        float acc = bp[d];
#pragma unroll 8
        for (int k = 0; k < DD; ++k) acc = fmaf(p[k], Wp[k * NT + d], acc);
        out[g * NT + d] = acc;
    }
}

extern "C" void kernel_launch(void* const* d_in, const int* in_sizes, int n_in,
                              void* d_out, int out_size, void* d_ws, size_t ws_size,
                              hipStream_t stream) {
    const int* x_atom = (const int*)d_in[0];
    const int* edge_index = (const int*)d_in[1];
    const int* edge_attr = (const int*)d_in[2];
    const int* batch = (const int*)d_in[3];
    const float* atom_emb = (const float*)d_in[4];
    const float* bond_emb = (const float*)d_in[5];
    const float* eps = (const float*)d_in[6];
    const float* W1 = (const float*)d_in[7];
    const float* b1 = (const float*)d_in[8];
    const float* g1 = (const float*)d_in[9];
    const float* bt1 = (const float*)d_in[10];
    const float* m1 = (const float*)d_in[11];
    const float* v1 = (const float*)d_in[12];
    const float* W2 = (const float*)d_in[13];
    const float* b2 = (const float*)d_in[14];
    const float* gO = (const float*)d_in[15];
    const float* btO = (const float*)d_in[16];
    const float* mO = (const float*)d_in[17];
    const float* vO = (const float*)d_in[18];
    const float* Wp = (const float*)d_in[19];
    const float* bp = (const float*)d_in[20];

    ushort_t* x16a = (ushort_t*)d_ws;        // N*D bf16
    ushort_t* x16b = x16a + NN * DD;         // N*D bf16
    ushort_t* h16 = x16b + NN * DD;          // N*D bf16
    ushort_t* W1P = h16 + NN * DD;           // NL*32768 bf16
    ushort_t* W2P = W1P + NL * 32768;        // NL*32768 bf16
    ushort_t* ebsum16 = W2P + NL * 32768;    // NL*512*128 bf16
    int* deg = (int*)(ebsum16 + NL * 65536); // 40000
    int* off = deg + NN;                     // 40064
    int* blk = off + 40064;                  // 512
    int* cursor = blk + 512;                 // 40000
    int* gbk = cursor + NN;                  // 128
    int2* epack = (int2*)(gbk + 128);        // NE int2
    int2* ebuf = epack + NE;                 // NE int2

    hipMemsetAsync(deg, 0, (NN + 40064 + 512 + NN + 128) * sizeof(int), stream);

    k_setup<<<23780, 256, 0, stream>>>(W1, W2, bond_emb, x_atom, atom_emb,
                                       edge_index, W1P, W2P, ebsum16, x16a, deg);
    k_scan1<<<157, 256, 0, stream>>>(deg, off, blk);
    k_scan2<<<1, 256, 0, stream>>>(blk);
    k_scan3<<<157, 256, 0, stream>>>(off, blk);
    k_bucket<<<NE / 1024, 256, 0, stream>>>(edge_index, edge_attr, off, gbk, ebuf);
    k_scatter2<<<NE / 256, 256, 0, stream>>>(ebuf, off, cursor, epack);

    for (int i = 0; i < NL; ++i) {
        ushort_t* xin = (i & 1) ? x16b : x16a;
        ushort_t* xout = (i & 1) ? x16a : x16b;
        k_gather<<<NN / 4, 256, 0, stream>>>(xin, off, epack, ebsum16 + i * 65536,
                                             eps, i, h16);
        k_mlp_mfma<<<NN / 32, 256, 0, stream>>>(
            h16, W1P + (size_t)i * 32768, W2P + (size_t)i * 32768, b1 + i * 256,
            g1 + i * 256, bt1 + i * 256, m1 + i * 256, v1 + i * 256, b2 + i * DD,
            gO + i * DD, btO + i * DD, mO + i * DD, vO + i * DD,
            (i < NL - 1) ? 1 : 0, xout);
    }
    k_poolhead<<<NG, DD, 0, stream>>>(x16b, batch, Wp, bp, (float*)d_out);
}

// Round 11
// 425.247 us; speedup vs baseline: 1.1055x; 1.1055x over previous
//
#include <hip/hip_runtime.h>
#include <hip/hip_bf16.h>

#define NN 40000
#define NE 640000
#define NG 2048
#define DD 128
#define NT 10
#define NL 5
#define NB 80  // dst buckets of 512 nodes

typedef __attribute__((ext_vector_type(8))) short short8;
typedef __attribute__((ext_vector_type(4))) float f32x4;
typedef unsigned short ushort_t;

static __device__ __forceinline__ ushort_t f2b(float f) {
    return __bfloat16_as_ushort(__float2bfloat16(f));
}
static __device__ __forceinline__ float b2f(ushort_t u) {
    return __bfloat162float(__ushort_as_bfloat16(u));
}

// ---------------- fused setup: tables + atom-encode + degree histogram -----
__global__ void __launch_bounds__(256)
k_setup(const float* __restrict__ W1, const float* __restrict__ W2,
        const float* __restrict__ bemb, const int* __restrict__ xa,
        const float* __restrict__ aemb, const int* __restrict__ ei,
        ushort_t* __restrict__ W1P, ushort_t* __restrict__ W2P,
        ushort_t* __restrict__ ebsum16, ushort_t* __restrict__ x16,
        int* __restrict__ deg) {
    int b = blockIdx.x, t = threadIdx.x;
    if (b < 1280) {
        int tid = b * 256 + t;  // < NL*65536
        int layer = tid >> 16;
        int r = tid & 65535;
        int half = r >> 15;
        int q = r & 32767;
        int j = q & 7;
        int lane = (q >> 3) & 63;
        if (half == 0) {
            int kk = (q >> 9) & 3;
            int nt = q >> 11;
            int n = nt * 16 + (lane & 15);
            int k = kk * 32 + (lane >> 4) * 8 + j;
            W1P[layer * 32768 + q] = f2b(W1[(layer * DD + k) * 256 + n]);
        } else {
            int kk = (q >> 9) & 7;
            int nt = q >> 12;
            int n = nt * 16 + (lane & 15);
            int k = kk * 32 + (lane >> 4) * 8 + j;
            W2P[layer * 32768 + q] = f2b(W2[(layer * 256 + k) * DD + n]);
        }
        int d = tid & 127;
        int c = (tid >> 7) & 511;
        const float* bl = bemb + (size_t)layer * 3 * 8 * DD;
        ebsum16[tid] = f2b(bl[(c & 7) * DD + d] + bl[(8 + ((c >> 3) & 7)) * DD + d] +
                           bl[(16 + (c >> 6)) * DD + d]);
    } else if (b < 21280) {
        int half = t >> 7, d = t & 127;
        int n = (b - 1280) * 2 + half;
        __shared__ int idx[2][9];
        if (d < 9) idx[half][d] = xa[n * 9 + d];
        __syncthreads();
        float s = 0.f;
#pragma unroll
        for (int f = 0; f < 9; ++f) s += aemb[(f * 64 + idx[half][f]) * DD + d];
        x16[n * DD + d] = f2b(s);
    } else {
        int e = (b - 21280) * 256 + t;
        atomicAdd(&deg[ei[NE + e]], 1);
    }
}

// ---------------- CSR build -----------------------------------------------

__global__ void k_scan1(const int* __restrict__ deg, int* __restrict__ off,
                        int* __restrict__ blksum) {
    int b = blockIdx.x, t = threadIdx.x;
    int i = b * 256 + t;
    __shared__ int s[256];
    int v = (i < NN) ? deg[i] : 0;
    s[t] = v;
    __syncthreads();
    for (int d = 1; d < 256; d <<= 1) {
        int add = (t >= d) ? s[t - d] : 0;
        __syncthreads();
        s[t] += add;
        __syncthreads();
    }
    if (i <= NN) off[i] = s[t] - v;
    if (t == 255) blksum[b] = s[255];
}

__global__ void k_scan2(int* __restrict__ blk) {
    int t = threadIdx.x;
    __shared__ int s[256];
    int v = blk[t];
    s[t] = v;
    __syncthreads();
    for (int d = 1; d < 256; d <<= 1) {
        int add = (t >= d) ? s[t - d] : 0;
        __syncthreads();
        s[t] += add;
        __syncthreads();
    }
    blk[256 + t] = s[t] - v;  // exclusive
}

__global__ void k_scan3(int* __restrict__ off, const int* __restrict__ blk) {
    int b = blockIdx.x, t = threadIdx.x;
    int i = b * 256 + t;
    if (i <= NN) off[i] += blk[256 + b];
}

// Phase A: bin edges by dst bucket into dense runs of ebuf.
__global__ void __launch_bounds__(256)
k_bucket(const int* __restrict__ ei, const int* __restrict__ ea,
         const int* __restrict__ off, int* __restrict__ gbk,
         int2* __restrict__ ebuf) {
    __shared__ int hist[NB];
    __shared__ int sbase[NB];
    int t = threadIdx.x;
    int e0 = blockIdx.x * 1024;
    if (t < NB) hist[t] = 0;
    __syncthreads();
    int rank[4], buck[4], rec[4], dstv[4];
#pragma unroll
    for (int k = 0; k < 4; ++k) {
        int e = e0 + k * 256 + t;
        int src = ei[e];
        int dst = ei[NE + e];
        int a0 = ea[e * 3 + 0], a1 = ea[e * 3 + 1], a2 = ea[e * 3 + 2];
        rec[k] = src | ((a0 | (a1 << 3) | (a2 << 6)) << 16);
        dstv[k] = dst;
        int b = dst >> 9;
        buck[k] = b;
        rank[k] = atomicAdd(&hist[b], 1);
    }
    __syncthreads();
    if (t < NB) sbase[t] = atomicAdd(&gbk[t], hist[t]);
    __syncthreads();
#pragma unroll
    for (int k = 0; k < 4; ++k) {
        int b = buck[k];
        int slot = off[b << 9] + sbase[b] + rank[k];
        ebuf[slot] = make_int2(rec[k], dstv[k]);
    }
}

// Phase B: scatter within L2-resident bucket windows.
__global__ void k_scatter2(const int2* __restrict__ ebuf, const int* __restrict__ off,
                           int* __restrict__ cursor, int2* __restrict__ epack) {
    int i = blockIdx.x * 256 + threadIdx.x;
    int2 s = ebuf[i];
    int dst = s.y;
    int p = off[dst] + atomicAdd(&cursor[dst], 1);
    epack[p] = make_int2(s.x & 0xFFFF, s.x >> 16);
}

// Gather: wave per node, lane handles 2 dims (ushort2). 4 nodes/block.
// Edge loop unrolled x4 with epack software pipeline (unmasked, scalar tail).
__global__ void __launch_bounds__(256)
k_gather(const ushort_t* __restrict__ xin, const int* __restrict__ off,
         const int2* __restrict__ epack, const ushort_t* __restrict__ ebsum16,
         const float* __restrict__ eps, int layer, ushort_t* __restrict__ h16) {
    int t = threadIdx.x;
    int lane = t & 63;
    int n = blockIdx.x * 4 + (t >> 6);
    const ushort2* x2 = (const ushort2*)xin;
    const ushort2* eb2 = (const ushort2*)ebsum16;
    ushort2 xv = x2[n * 64 + lane];
    float es = 1.f + eps[layer];
    float ax = es * b2f(xv.x), ay = es * b2f(xv.y);
    int p = off[n], p1 = off[n + 1];

    int2 e0, e1, e2, e3;
    bool have = (p + 4 <= p1);
    if (have) { e0 = epack[p]; e1 = epack[p + 1]; e2 = epack[p + 2]; e3 = epack[p + 3]; }
    while (have) {
        int np = p + 4;
        bool nh = (np + 4 <= p1);
        int2 f0, f1, f2, f3;
        if (nh) { f0 = epack[np]; f1 = epack[np + 1]; f2 = epack[np + 2]; f3 = epack[np + 3]; }
        ushort2 v0 = eb2[e0.y * 64 + lane];
        ushort2 s0 = x2[e0.x * 64 + lane];
        ushort2 v1 = eb2[e1.y * 64 + lane];
        ushort2 s1 = x2[e1.x * 64 + lane];
        ushort2 v2 = eb2[e2.y * 64 + lane];
        ushort2 s2 = x2[e2.x * 64 + lane];
        ushort2 v3 = eb2[e3.y * 64 + lane];
        ushort2 s3 = x2[e3.x * 64 + lane];
        ax += fmaxf(b2f(v0.x) + b2f(s0.x), 0.f) + fmaxf(b2f(v1.x) + b2f(s1.x), 0.f) +
              fmaxf(b2f(v2.x) + b2f(s2.x), 0.f) + fmaxf(b2f(v3.x) + b2f(s3.x), 0.f);
        ay += fmaxf(b2f(v0.y) + b2f(s0.y), 0.f) + fmaxf(b2f(v1.y) + b2f(s1.y), 0.f) +
              fmaxf(b2f(v2.y) + b2f(s2.y), 0.f) + fmaxf(b2f(v3.y) + b2f(s3.y), 0.f);
        p = np;
        e0 = f0; e1 = f1; e2 = f2; e3 = f3;
        have = nh;
    }
    for (; p < p1; ++p) {
        int2 er = epack[p];
        ushort2 ev = eb2[er.y * 64 + lane];
        ushort2 sv = x2[er.x * 64 + lane];
        ax += fmaxf(b2f(ev.x) + b2f(sv.x), 0.f);
        ay += fmaxf(b2f(ev.y) + b2f(sv.y), 0.f);
    }
    ushort2 o;
    o.x = f2b(ax);
    o.y = f2b(ay);
    ((ushort2*)h16)[n * 64 + lane] = o;
}

// Fused MLP on MFMA: 32 nodes per block, 256 threads (4 waves). Each B-frag
// load feeds 2 MFMAs (two A row-tiles).
__global__ void __launch_bounds__(256)
k_mlp_mfma(const ushort_t* __restrict__ h16, const ushort_t* __restrict__ W1P,
           const ushort_t* __restrict__ W2P, const float* __restrict__ b1,
           const float* __restrict__ g1, const float* __restrict__ bt1,
           const float* __restrict__ m1, const float* __restrict__ v1,
           const float* __restrict__ b2_, const float* __restrict__ gO,
           const float* __restrict__ btO, const float* __restrict__ mO,
           const float* __restrict__ vO, int relu, ushort_t* __restrict__ xout) {
    __shared__ ushort_t aS[32 * 136];   // 32 rows x 128 (pad +8)
    __shared__ ushort_t mid[32 * 264];  // 32 rows x 256 (pad +8)
    int t = threadIdx.x;
    int wave = t >> 6, lane = t & 63;
    int row0 = blockIdx.x * 32;
    int lrow = lane & 15, quad = lane >> 4;

#pragma unroll
    for (int ps = 0; ps < 2; ++ps) {
        int idx = ps * 256 + t;
        int r = idx >> 4, c = (idx & 15) * 8;
        *(short8*)&aS[r * 136 + c] = *(const short8*)&h16[(row0 + r) * DD + c];
    }
    __syncthreads();

    f32x4 acc1[2][4];
#pragma unroll
    for (int rt = 0; rt < 2; ++rt)
#pragma unroll
        for (int i = 0; i < 4; ++i) acc1[rt][i] = (f32x4){0.f, 0.f, 0.f, 0.f};
#pragma unroll
    for (int kk = 0; kk < 4; ++kk) {
        short8 af0 = *(const short8*)&aS[lrow * 136 + kk * 32 + quad * 8];
        short8 af1 = *(const short8*)&aS[(16 + lrow) * 136 + kk * 32 + quad * 8];
#pragma unroll
        for (int i = 0; i < 4; ++i) {
            int nt = wave * 4 + i;
            short8 bf = *(const short8*)&W1P[((nt * 4 + kk) * 64 + lane) * 8];
            acc1[0][i] = __builtin_amdgcn_mfma_f32_16x16x32_bf16(af0, bf, acc1[0][i], 0, 0, 0);
            acc1[1][i] = __builtin_amdgcn_mfma_f32_16x16x32_bf16(af1, bf, acc1[1][i], 0, 0, 0);
        }
    }
#pragma unroll
    for (int i = 0; i < 4; ++i) {
        int col = (wave * 4 + i) * 16 + lrow;
        float s1 = g1[col] * rsqrtf(v1[col] + 1e-5f);
        float sh = bt1[col] - (m1[col] - b1[col]) * s1;
#pragma unroll
        for (int rt = 0; rt < 2; ++rt)
#pragma unroll
            for (int r = 0; r < 4; ++r) {
                int row = rt * 16 + quad * 4 + r;
                float o = acc1[rt][i][r] * s1 + sh;
                mid[row * 264 + col] = f2b(fmaxf(o, 0.f));
            }
    }
    __syncthreads();

    f32x4 acc2[2][2];
#pragma unroll
    for (int rt = 0; rt < 2; ++rt)
#pragma unroll
        for (int i = 0; i < 2; ++i) acc2[rt][i] = (f32x4){0.f, 0.f, 0.f, 0.f};
#pragma unroll
    for (int kk = 0; kk < 8; ++kk) {
        short8 af0 = *(const short8*)&mid[lrow * 264 + kk * 32 + quad * 8];
        short8 af1 = *(const short8*)&mid[(16 + lrow) * 264 + kk * 32 + quad * 8];
#pragma unroll
        for (int i = 0; i < 2; ++i) {
            int nt = wave * 2 + i;
            short8 bf = *(const short8*)&W2P[((nt * 8 + kk) * 64 + lane) * 8];
            acc2[0][i] = __builtin_amdgcn_mfma_f32_16x16x32_bf16(af0, bf, acc2[0][i], 0, 0, 0);
            acc2[1][i] = __builtin_amdgcn_mfma_f32_16x16x32_bf16(af1, bf, acc2[1][i], 0, 0, 0);
        }
    }
#pragma unroll
    for (int i = 0; i < 2; ++i) {
        int col = (wave * 2 + i) * 16 + lrow;
        float s = gO[col] * rsqrtf(vO[col] + 1e-5f);
        float sh = btO[col] - (mO[col] - b2_[col]) * s;
#pragma unroll
        for (int rt = 0; rt < 2; ++rt)
#pragma unroll
            for (int r = 0; r < 4; ++r) {
                int row = rt * 16 + quad * 4 + r;
                float o = acc2[rt][i][r] * s + sh;
                if (relu) o = fmaxf(o, 0.f);
                xout[(row0 + row) * DD + col] = f2b(o);
            }
    }
}

// Fused pool+head: block g reduces its node range, then computes out[g].
__global__ void k_poolhead(const ushort_t* __restrict__ x16,
                           const int* __restrict__ batch,
                           const float* __restrict__ Wp, const float* __restrict__ bp,
                           float* __restrict__ out) {
    int g = blockIdx.x, d = threadIdx.x;  // 128 threads
    int lo = 0, hi = NN;
    while (lo < hi) { int m = (lo + hi) >> 1; if (batch[m] < g) lo = m + 1; else hi = m; }
    int start = lo;
    hi = NN;
    while (lo < hi) { int m = (lo + hi) >> 1; if (batch[m] < g + 1) lo = m + 1; else hi = m; }
    int end = lo;
    float s = 0.f;
    for (int n = start; n < end; ++n) s += b2f(x16[n * DD + d]);
    float c = fmaxf((float)(end - start), 1.f);
    __shared__ float p[DD];
    p[d] = s / c;
    __syncthreads();
    if (d < NT) {
        float acc = bp[d];
#pragma unroll 8
        for (int k = 0; k < DD; ++k) acc = fmaf(p[k], Wp[k * NT + d], acc);
        out[g * NT + d] = acc;
    }
}

extern "C" void kernel_launch(void* const* d_in, const int* in_sizes, int n_in,
                              void* d_out, int out_size, void* d_ws, size_t ws_size,
                              hipStream_t stream) {
    const int* x_atom = (const int*)d_in[0];
    const int* edge_index = (const int*)d_in[1];
    const int* edge_attr = (const int*)d_in[2];
    const int* batch = (const int*)d_in[3];
    const float* atom_emb = (const float*)d_in[4];
    const float* bond_emb = (const float*)d_in[5];
    const float* eps = (const float*)d_in[6];
    const float* W1 = (const float*)d_in[7];
    const float* b1 = (const float*)d_in[8];
    const float* g1 = (const float*)d_in[9];
    const float* bt1 = (const float*)d_in[10];
    const float* m1 = (const float*)d_in[11];
    const float* v1 = (const float*)d_in[12];
    const float* W2 = (const float*)d_in[13];
    const float* b2 = (const float*)d_in[14];
    const float* gO = (const float*)d_in[15];
    const float* btO = (const float*)d_in[16];
    const float* mO = (const float*)d_in[17];
    const float* vO = (const float*)d_in[18];
    const float* Wp = (const float*)d_in[19];
    const float* bp = (const float*)d_in[20];

    ushort_t* x16a = (ushort_t*)d_ws;        // N*D bf16
    ushort_t* x16b = x16a + NN * DD;         // N*D bf16
    ushort_t* h16 = x16b + NN * DD;          // N*D bf16
    ushort_t* W1P = h16 + NN * DD;           // NL*32768 bf16
    ushort_t* W2P = W1P + NL * 32768;        // NL*32768 bf16
    ushort_t* ebsum16 = W2P + NL * 32768;    // NL*512*128 bf16
    int* deg = (int*)(ebsum16 + NL * 65536); // 40000
    int* off = deg + NN;                     // 40064
    int* blk = off + 40064;                  // 512
    int* cursor = blk + 512;                 // 40000
    int* gbk = cursor + NN;                  // 128
    int2* epack = (int2*)(gbk + 128);        // NE int2
    int2* ebuf = epack + NE;                 // NE int2

    hipMemsetAsync(deg, 0, (NN + 40064 + 512 + NN + 128) * sizeof(int), stream);

    k_setup<<<23780, 256, 0, stream>>>(W1, W2, bond_emb, x_atom, atom_emb,
                                       edge_index, W1P, W2P, ebsum16, x16a, deg);
    k_scan1<<<157, 256, 0, stream>>>(deg, off, blk);
    k_scan2<<<1, 256, 0, stream>>>(blk);
    k_scan3<<<157, 256, 0, stream>>>(off, blk);
    k_bucket<<<NE / 1024, 256, 0, stream>>>(edge_index, edge_attr, off, gbk, ebuf);
    k_scatter2<<<NE / 256, 256, 0, stream>>>(ebuf, off, cursor, epack);

    for (int i = 0; i < NL; ++i) {
        ushort_t* xin = (i & 1) ? x16b : x16a;
        ushort_t* xout = (i & 1) ? x16a : x16b;
        k_gather<<<NN / 4, 256, 0, stream>>>(xin, off, epack, ebsum16 + i * 65536,
                                             eps, i, h16);
        k_mlp_mfma<<<NN / 32, 256, 0, stream>>>(
            h16, W1P + (size_t)i * 32768, W2P + (size_t)i * 32768, b1 + i * 256,
            g1 + i * 256, bt1 + i * 256, m1 + i * 256, v1 + i * 256, b2 + i * DD,
            gO + i * DD, btO + i * DD, mO + i * DD, vO + i * DD,
            (i < NL - 1) ? 1 : 0, xout);
    }
    k_poolhead<<<NG, DD, 0, stream>>>(x16b, batch, Wp, bp, (float*)d_out);
}